// Round 9
// baseline (903.802 us; speedup 1.0000x reference)
//
#include <hip/hip_runtime.h>
#include <hip/hip_fp16.h>
#include <hip/hip_cooperative_groups.h>
#include <math.h>

namespace cg = cooperative_groups;

// ---------------- problem constants ----------------
constexpr int NN   = 50000;          // nodes
constexpr int NE   = 800000;         // edges (before self loops)
constexpr int ETOT = NE + NN;        // 850000 with self loops
constexpr int F_IN = 128;
constexpr int HID  = 64;
constexpr int HEADS = 4;
constexpr int HC1  = HEADS * HID;    // 256
constexpr int NG   = 64;             // graphs
constexpr float SLOPE = 0.2f;
constexpr int TW_TOT = F_IN * HC1 + HC1 * HID;   // transpose work items (49152)
constexpr int SCAN_B = 196;                       // scan chunks (196*256 >= NN)

typedef _Float16 half8 __attribute__((ext_vector_type(8)));
typedef float f32x4 __attribute__((ext_vector_type(4)));

__device__ __forceinline__ float lrelu(float v) { return v >= 0.f ? v : SLOPE * v; }
__device__ __forceinline__ float elu(float v) { return v > 0.f ? v : expm1f(v); }

// pack 8 floats -> 8 fp16 as one uint4
__device__ __forceinline__ uint4 pack8_h(const float* v) {
  union { __half2 h[4]; uint4 u; } pk;
  pk.h[0] = __floats2half2_rn(v[0], v[1]);
  pk.h[1] = __floats2half2_rn(v[2], v[3]);
  pk.h[2] = __floats2half2_rn(v[4], v[5]);
  pk.h[3] = __floats2half2_rn(v[6], v[7]);
  return pk.u;
}

// ================= cooperative CSR mega-kernel =================
// One dispatch: zero -> histogram(4-way)+weight transpose -> 3-stage scan -> scatter.
// Grid 1024x256 (4 blocks/CU: co-residency safe), grid-stride loops.
__global__ __launch_bounds__(256) void csr_coop_kernel(
    const int* __restrict__ esrc, const int* __restrict__ edst,
    const float* __restrict__ W1, const float* __restrict__ W2,
    __half* __restrict__ W1T, __half* __restrict__ W2T,
    int* __restrict__ deg4, int* __restrict__ cursor4,     // contiguous 8*NN
    int* __restrict__ rowptr, int4* __restrict__ qoff,
    int* __restrict__ psum, const int* __restrict__ batch,
    int* __restrict__ gstart, int* __restrict__ ssorted) {
  cg::grid_group grid = cg::this_grid();
  __shared__ int wsum[4];
  const int T   = gridDim.x * blockDim.x;
  const int tid = blockIdx.x * blockDim.x + threadIdx.x;

  // phase 0: zero deg4 + cursor4
  for (int i = tid; i < 8 * NN; i += T) deg4[i] = 0;
  grid.sync();

  // phase 1: 4-way split degree histogram + weight transposes
  for (int idx = tid; idx < ETOT + TW_TOT; idx += T) {
    if (idx < ETOT) {
      int d = (idx < NE) ? edst[idx] : (idx - NE);
      atomicAdd(&deg4[(idx & 3) * NN + d], 1);
    } else {
      int i = idx - ETOT;
      if (i < F_IN * HC1) {                     // W1 [128][256] -> W1T [256][128]
        int k = i / HC1, n = i - k * HC1;
        W1T[n * F_IN + k] = __float2half(W1[i]);
      } else {                                  // W2 [256][64] -> W2T [64][256]
        int j = i - F_IN * HC1;
        int k = j / HID, n = j - k * HID;
        W2T[n * HC1 + k] = __float2half(W2[j]);
      }
    }
  }
  grid.sync();

  // phase 2a: per-chunk scan (blocks 0..SCAN_B-1), quarter offsets
  if (blockIdx.x < SCAN_B) {
    const int t = threadIdx.x, lane = t & 63, w = t >> 6;
    const int i = blockIdx.x * 256 + t;
    int d0 = 0, d1 = 0, d2 = 0, d3 = 0;
    if (i < NN) {
      d0 = deg4[i]; d1 = deg4[NN + i]; d2 = deg4[2 * NN + i]; d3 = deg4[3 * NN + i];
      qoff[i] = make_int4(0, d0, d0 + d1, d0 + d1 + d2);
    }
    int sv = d0 + d1 + d2 + d3;
#pragma unroll
    for (int o = 1; o < 64; o <<= 1) {
      int u = __shfl_up(sv, o, 64);
      if (lane >= o) sv += u;
    }
    if (lane == 63) wsum[w] = sv;
    __syncthreads();
    if (t == 0) {
      int a = wsum[0];
      wsum[0] = 0;
      int b = a + wsum[1]; wsum[1] = a;
      a = b + wsum[2]; wsum[2] = b;
      b = a + wsum[3]; wsum[3] = a;
      psum[blockIdx.x] = b;
    }
    __syncthreads();
    if (i < NN) rowptr[i + 1] = sv + wsum[w];
  }
  grid.sync();

  // phase 2b: top scan (block 0) + graph boundaries
  if (blockIdx.x == 0) {
    const int t = threadIdx.x, lane = t & 63, w = t >> 6;
    int v = (t < SCAN_B) ? psum[t] : 0;
    int sv = v;
#pragma unroll
    for (int o = 1; o < 64; o <<= 1) {
      int u = __shfl_up(sv, o, 64);
      if (lane >= o) sv += u;
    }
    if (lane == 63) wsum[w] = sv;
    __syncthreads();
    if (t == 0) {
      int a = wsum[0];
      wsum[0] = 0;
      int b = a + wsum[1]; wsum[1] = a;
      a = b + wsum[2]; wsum[2] = b;
      wsum[3] = a;
      rowptr[0] = 0;
    }
    __syncthreads();
    if (t < SCAN_B) psum[t] = sv - v + wsum[w];   // exclusive chunk offset
    if (t < NG + 1) {
      int g = t, lo = 0, hi = NN;
      while (lo < hi) { int mid = (lo + hi) >> 1; if (batch[mid] < g) lo = mid + 1; else hi = mid; }
      gstart[g] = lo;
    }
  }
  grid.sync();

  // phase 2c: add chunk offsets
  for (int i = tid; i < NN; i += T) rowptr[i + 1] += psum[i >> 8];
  grid.sync();

  // phase 3: scatter with 4-way cursors
  for (int e = tid; e < ETOT; e += T) {
    int s = (e < NE) ? esrc[e] : (e - NE);
    int d = (e < NE) ? edst[e] : (e - NE);
    int q = e & 3;
    int4 qo = qoff[d];
    int base = (q == 0) ? qo.x : (q == 1) ? qo.y : (q == 2) ? qo.z : qo.w;
    int slot = rowptr[d] + base + atomicAdd(&cursor4[q * NN + d], 1);
    ssorted[slot] = s;
  }
}

// ================= gemm1 (MFMA): h1 = fp16(x @ W1), + attention scores =================
__global__ __launch_bounds__(256) void gemm1_mfma(
    const float* __restrict__ x, const __half* __restrict__ W1T,
    const float* __restrict__ asrc, const float* __restrict__ adst,
    __half* __restrict__ h1, float* __restrict__ ssrc, float* __restrict__ sdst) {
  __shared__ float hs[16][HC1 + 1];
  const int m0 = blockIdx.x * 16;
  const int t = threadIdx.x;
  const int wv = t >> 6, lane = t & 63;
  const int lm = lane & 15, quad = lane >> 4;
  const int n0 = wv * 64;
  f32x4 acc[4] = {{0.f,0.f,0.f,0.f},{0.f,0.f,0.f,0.f},{0.f,0.f,0.f,0.f},{0.f,0.f,0.f,0.f}};
  const float* arow = x + (size_t)(m0 + lm) * F_IN + quad * 8;
#pragma unroll
  for (int kc = 0; kc < F_IN; kc += 32) {
    float4 u = *(const float4*)(arow + kc);
    float4 v = *(const float4*)(arow + kc + 4);
    half8 a;
    a[0]=(_Float16)u.x; a[1]=(_Float16)u.y; a[2]=(_Float16)u.z; a[3]=(_Float16)u.w;
    a[4]=(_Float16)v.x; a[5]=(_Float16)v.y; a[6]=(_Float16)v.z; a[7]=(_Float16)v.w;
#pragma unroll
    for (int tn = 0; tn < 4; ++tn) {
      half8 b = *(const half8*)(W1T + (size_t)(n0 + tn * 16 + lm) * F_IN + kc + quad * 8);
      acc[tn] = __builtin_amdgcn_mfma_f32_16x16x32_f16(a, b, acc[tn], 0, 0, 0);
    }
  }
#pragma unroll
  for (int tn = 0; tn < 4; ++tn)
#pragma unroll
    for (int r = 0; r < 4; ++r)
      hs[quad * 4 + r][n0 + tn * 16 + lm] = acc[tn][r];
  __syncthreads();
  {
    __half2* h1h = (__half2*)(h1 + (size_t)m0 * HC1);
    int c2 = t & 127, rbase = (t >> 7) * 8;
#pragma unroll
    for (int r = 0; r < 8; ++r) {
      int row = rbase + r;
      h1h[row * 128 + c2] = __floats2half2_rn(hs[row][2 * c2], hs[row][2 * c2 + 1]);
    }
  }
  if (t < 128) {
    int r = t >> 3, hh = (t >> 1) & 3, isdst = t & 1;
    const float* a = isdst ? adst : asrc;
    float s = 0.f;
    for (int c = 0; c < HID; ++c) s += hs[r][hh * HID + c] * a[hh * HID + c];
    (isdst ? sdst : ssrc)[(m0 + r) * HEADS + hh] = s;
  }
}

// ================= gemm2 (MFMA): h2 = fp16(o1 @ W2), + attention scores =================
// one wave per block; 16 rows x 64 cols (4 mfma tiles), K=256 in 8 chunks.
__global__ __launch_bounds__(64) void gemm2_mfma(
    const __half* __restrict__ o1h, const __half* __restrict__ W2T,
    const float* __restrict__ asrc, const float* __restrict__ adst,
    __half* __restrict__ h2, float* __restrict__ ssrc, float* __restrict__ sdst) {
  __shared__ float hs[16][HID + 1];
  const int m0 = blockIdx.x * 16;
  const int lane = threadIdx.x;
  const int lm = lane & 15, quad = lane >> 4;
  f32x4 acc[4] = {{0.f,0.f,0.f,0.f},{0.f,0.f,0.f,0.f},{0.f,0.f,0.f,0.f},{0.f,0.f,0.f,0.f}};
  const __half* arow = o1h + (size_t)(m0 + lm) * HC1 + quad * 8;
#pragma unroll
  for (int kc = 0; kc < HC1; kc += 32) {
    half8 a = *(const half8*)(arow + kc);
#pragma unroll
    for (int tn = 0; tn < 4; ++tn) {
      half8 b = *(const half8*)(W2T + (size_t)(tn * 16 + lm) * HC1 + kc + quad * 8);
      acc[tn] = __builtin_amdgcn_mfma_f32_16x16x32_f16(a, b, acc[tn], 0, 0, 0);
    }
  }
#pragma unroll
  for (int tn = 0; tn < 4; ++tn)
#pragma unroll
    for (int r = 0; r < 4; ++r)
      hs[quad * 4 + r][tn * 16 + lm] = acc[tn][r];
  __syncthreads();
  {
    __half2* h2h = (__half2*)(h2 + (size_t)m0 * HID);
    int c2 = lane & 31, rbase = (lane >> 5) * 8;
#pragma unroll
    for (int r = 0; r < 8; ++r) {
      int row = rbase + r;
      h2h[row * 32 + c2] = __floats2half2_rn(hs[row][2 * c2], hs[row][2 * c2 + 1]);
    }
  }
  if (lane < 32) {
    int r = lane >> 1, isdst = lane & 1;
    const float* a = isdst ? adst : asrc;
    float s = 0.f;
    for (int c = 0; c < HID; ++c) s += hs[r][c] * a[c];
    (isdst ? sdst : ssrc)[m0 + r] = s;
  }
}

// ================= fused GAT gather, layer 1 (H=4): one wave per dst, no barrier =======
// Score phase: lane = j*4+h handles (edge j, head h), 16 edges/pass.
// Agg phase: 2 edges in flight: eg=lane>>5 takes edge j+eg; cpos=lane&31 covers
// 16B (8 fp16 channels) of the 512B row; head = cpos>>3. Output o1 in fp16.
__global__ __launch_bounds__(256) void gat_gather4_kernel(
    const int* __restrict__ rowptr, const int* __restrict__ ssorted,
    const float* __restrict__ ss, const float* __restrict__ sd,
    const __half* __restrict__ h, const float* __restrict__ bias,
    __half* __restrict__ outp) {
  const int d    = (blockIdx.x * 256 + threadIdx.x) >> 6;
  const int lane = threadIdx.x & 63;
  if (d >= NN) return;
  const int start = rowptr[d];
  const int deg   = rowptr[d + 1] - start;
  const int hsel  = lane & 3;     // score-phase head
  const int eg    = lane >> 5;    // agg edge subgroup (0/1)
  const int cpos  = lane & 31;    // 16B chunk within row
  const int hh    = cpos >> 3;    // agg-phase head
  const float sdv = sd[d * 4 + hsel];
  float accv[8] = {0.f,0.f,0.f,0.f,0.f,0.f,0.f,0.f};

  if (deg <= 32) {
    const int j0 = lane >> 2;
    int s0 = 0, s1 = 0;
    float v0 = -INFINITY, v1 = -INFINITY;
    if (j0 < deg)      { s0 = ssorted[start + j0];      v0 = lrelu(ss[s0 * 4 + hsel] + sdv); }
    if (j0 + 16 < deg) { s1 = ssorted[start + j0 + 16]; v1 = lrelu(ss[s1 * 4 + hsel] + sdv); }
    float mx = fmaxf(v0, v1);
#pragma unroll
    for (int o = 4; o < 64; o <<= 1) mx = fmaxf(mx, __shfl_xor(mx, o, 64));
    float p0 = (j0 < deg)      ? __expf(v0 - mx) : 0.f;
    float p1 = (j0 + 16 < deg) ? __expf(v1 - mx) : 0.f;
    float den = p0 + p1;
#pragma unroll
    for (int o = 4; o < 64; o <<= 1) den += __shfl_xor(den, o, 64);
    const float inv = 1.f / (den + 1e-16f);
    const float pa0 = p0 * inv, pa1 = p1 * inv;
    const int m1 = min(deg, 16);
    for (int j = 0; j < m1; j += 2) {
      int jj = j + eg;
      float alpha = (jj < m1) ? __shfl(pa0, jj * 4 + hh, 64) : 0.f;
      int   sj    = __shfl(s0, (jj < 16 ? jj : 15) * 4, 64);
      uint4 u = *(const uint4*)(h + (size_t)sj * HC1 + cpos * 8);
      float2 f0 = __half22float2(*(const __half2*)&u.x);
      float2 f1 = __half22float2(*(const __half2*)&u.y);
      float2 f2 = __half22float2(*(const __half2*)&u.z);
      float2 f3 = __half22float2(*(const __half2*)&u.w);
      accv[0] += alpha * f0.x; accv[1] += alpha * f0.y;
      accv[2] += alpha * f1.x; accv[3] += alpha * f1.y;
      accv[4] += alpha * f2.x; accv[5] += alpha * f2.y;
      accv[6] += alpha * f3.x; accv[7] += alpha * f3.y;
    }
    for (int j = 16; j < deg; j += 2) {
      int jj = j + eg - 16;
      float alpha = (jj + 16 < deg) ? __shfl(pa1, jj * 4 + hh, 64) : 0.f;
      int   sj    = __shfl(s1, (jj < 16 ? jj : 15) * 4, 64);
      uint4 u = *(const uint4*)(h + (size_t)sj * HC1 + cpos * 8);
      float2 f0 = __half22float2(*(const __half2*)&u.x);
      float2 f1 = __half22float2(*(const __half2*)&u.y);
      float2 f2 = __half22float2(*(const __half2*)&u.z);
      float2 f3 = __half22float2(*(const __half2*)&u.w);
      accv[0] += alpha * f0.x; accv[1] += alpha * f0.y;
      accv[2] += alpha * f1.x; accv[3] += alpha * f1.y;
      accv[4] += alpha * f2.x; accv[5] += alpha * f2.y;
      accv[6] += alpha * f3.x; accv[7] += alpha * f3.y;
    }
  } else {
    // chunked (rare)
    float mx = -INFINITY;
    for (int base = 0; base < deg; base += 16) {
      int j = base + (lane >> 2);
      float v = (j < deg) ? lrelu(ss[ssorted[start + j] * 4 + hsel] + sdv) : -INFINITY;
#pragma unroll
      for (int o = 4; o < 64; o <<= 1) v = fmaxf(v, __shfl_xor(v, o, 64));
      mx = fmaxf(mx, v);
    }
    float den = 0.f;
    for (int base = 0; base < deg; base += 16) {
      int j = base + (lane >> 2);
      float p = (j < deg) ? __expf(lrelu(ss[ssorted[start + j] * 4 + hsel] + sdv) - mx) : 0.f;
#pragma unroll
      for (int o = 4; o < 64; o <<= 1) p += __shfl_xor(p, o, 64);
      den += p;
    }
    const float inv = 1.f / (den + 1e-16f);
    for (int base = 0; base < deg; base += 16) {
      int j = base + (lane >> 2);
      int s = 0; float pa = 0.f;
      if (j < deg) {
        s = ssorted[start + j];
        pa = __expf(lrelu(ss[s * 4 + hsel] + sdv) - mx) * inv;
      }
      int cnt = min(16, deg - base);
      for (int jc = 0; jc < cnt; jc += 2) {
        int jj = jc + eg;
        float alpha = (jj < cnt) ? __shfl(pa, jj * 4 + hh, 64) : 0.f;
        int   sj    = __shfl(s, (jj < 16 ? jj : 15) * 4, 64);
        uint4 u = *(const uint4*)(h + (size_t)sj * HC1 + cpos * 8);
        float2 f0 = __half22float2(*(const __half2*)&u.x);
        float2 f1 = __half22float2(*(const __half2*)&u.y);
        float2 f2 = __half22float2(*(const __half2*)&u.z);
        float2 f3 = __half22float2(*(const __half2*)&u.w);
        accv[0] += alpha * f0.x; accv[1] += alpha * f0.y;
        accv[2] += alpha * f1.x; accv[3] += alpha * f1.y;
        accv[4] += alpha * f2.x; accv[5] += alpha * f2.y;
        accv[6] += alpha * f3.x; accv[7] += alpha * f3.y;
      }
    }
  }
  // combine the two edge subgroups, then lanes 0..31 write the 512B fp16 row
#pragma unroll
  for (int k = 0; k < 8; ++k) accv[k] += __shfl_xor(accv[k], 32, 64);
  if (eg == 0) {
    float e[8];
#pragma unroll
    for (int k = 0; k < 8; ++k) e[k] = elu(accv[k] + bias[cpos * 8 + k]);
    *(uint4*)(outp + (size_t)d * HC1 + cpos * 8) = pack8_h(e);
  }
}

// ================= fused GAT gather, layer 2 (H=1): one wave per dst =================
__global__ __launch_bounds__(256) void gat_gather1_kernel(
    const int* __restrict__ rowptr, const int* __restrict__ ssorted,
    const float* __restrict__ ss, const float* __restrict__ sd,
    const __half* __restrict__ h, const float* __restrict__ bias,
    float* __restrict__ outp) {
  const int d    = (blockIdx.x * 256 + threadIdx.x) >> 6;
  const int lane = threadIdx.x & 63;
  if (d >= NN) return;
  const int start = rowptr[d];
  const int deg   = rowptr[d + 1] - start;
  const int eg   = lane >> 3;     // edge subgroup (0..7)
  const int cpos = lane & 7;      // 16B chunk within 128B row
  const float sdv = sd[d];
  float accv[8] = {0.f,0.f,0.f,0.f,0.f,0.f,0.f,0.f};

  if (deg <= 64) {
    int s = 0; float v = -INFINITY;
    if (lane < deg) { s = ssorted[start + lane]; v = lrelu(ss[s] + sdv); }
    float mx = v;
#pragma unroll
    for (int o = 1; o < 64; o <<= 1) mx = fmaxf(mx, __shfl_xor(mx, o, 64));
    float p = (lane < deg) ? __expf(v - mx) : 0.f;
    float den = p;
#pragma unroll
    for (int o = 1; o < 64; o <<= 1) den += __shfl_xor(den, o, 64);
    const float pa = p / (den + 1e-16f);
    for (int j = 0; j < deg; j += 8) {
      int jj = j + eg;
      float alpha = (jj < deg) ? __shfl(pa, jj < 63 ? jj : 63, 64) : 0.f;
      int   sj    = __shfl(s, jj < 63 ? jj : 63, 64);
      uint4 u = *(const uint4*)(h + (size_t)sj * HID + cpos * 8);
      float2 f0 = __half22float2(*(const __half2*)&u.x);
      float2 f1 = __half22float2(*(const __half2*)&u.y);
      float2 f2 = __half22float2(*(const __half2*)&u.z);
      float2 f3 = __half22float2(*(const __half2*)&u.w);
      accv[0] += alpha * f0.x; accv[1] += alpha * f0.y;
      accv[2] += alpha * f1.x; accv[3] += alpha * f1.y;
      accv[4] += alpha * f2.x; accv[5] += alpha * f2.y;
      accv[6] += alpha * f3.x; accv[7] += alpha * f3.y;
    }
  } else {
    float mx = -INFINITY;
    for (int base = 0; base < deg; base += 64) {
      int j = base + lane;
      float v = (j < deg) ? lrelu(ss[ssorted[start + j]] + sdv) : -INFINITY;
#pragma unroll
      for (int o = 1; o < 64; o <<= 1) v = fmaxf(v, __shfl_xor(v, o, 64));
      mx = fmaxf(mx, v);
    }
    float den = 0.f;
    for (int base = 0; base < deg; base += 64) {
      int j = base + lane;
      float p = (j < deg) ? __expf(lrelu(ss[ssorted[start + j]] + sdv) - mx) : 0.f;
#pragma unroll
      for (int o = 1; o < 64; o <<= 1) p += __shfl_xor(p, o, 64);
      den += p;
    }
    const float inv = 1.f / (den + 1e-16f);
    for (int base = 0; base < deg; base += 64) {
      int j = base + lane;
      int s = 0; float pa = 0.f;
      if (j < deg) { s = ssorted[start + j]; pa = __expf(lrelu(ss[s] + sdv) - mx) * inv; }
      int cnt = min(64, deg - base);
      for (int jc = 0; jc < cnt; jc += 8) {
        int jj = jc + eg;
        float alpha = (jj < cnt) ? __shfl(pa, jj < 63 ? jj : 63, 64) : 0.f;
        int   sj    = __shfl(s, jj < 63 ? jj : 63, 64);
        uint4 u = *(const uint4*)(h + (size_t)sj * HID + cpos * 8);
        float2 f0 = __half22float2(*(const __half2*)&u.x);
        float2 f1 = __half22float2(*(const __half2*)&u.y);
        float2 f2 = __half22float2(*(const __half2*)&u.z);
        float2 f3 = __half22float2(*(const __half2*)&u.w);
        accv[0] += alpha * f0.x; accv[1] += alpha * f0.y;
        accv[2] += alpha * f1.x; accv[3] += alpha * f1.y;
        accv[4] += alpha * f2.x; accv[5] += alpha * f2.y;
        accv[6] += alpha * f3.x; accv[7] += alpha * f3.y;
      }
    }
  }
#pragma unroll
  for (int o = 8; o < 64; o <<= 1) {
#pragma unroll
    for (int k = 0; k < 8; ++k) accv[k] += __shfl_xor(accv[k], o, 64);
  }
  if (eg == 0) {
    float4 r0, r1;
    r0.x = elu(accv[0] + bias[cpos * 8 + 0]);
    r0.y = elu(accv[1] + bias[cpos * 8 + 1]);
    r0.z = elu(accv[2] + bias[cpos * 8 + 2]);
    r0.w = elu(accv[3] + bias[cpos * 8 + 3]);
    r1.x = elu(accv[4] + bias[cpos * 8 + 4]);
    r1.y = elu(accv[5] + bias[cpos * 8 + 5]);
    r1.z = elu(accv[6] + bias[cpos * 8 + 6]);
    r1.w = elu(accv[7] + bias[cpos * 8 + 7]);
    float* op = outp + (size_t)d * HID + cpos * 8;
    *(float4*)op = r0;
    *(float4*)(op + 4) = r1;
  }
}

// ---------------- fused pool + FC + log_softmax: one block per graph ----------------
__global__ __launch_bounds__(256) void pool_head_kernel(const float* __restrict__ o2,
                                                        const int* __restrict__ gstart,
                                                        const float* __restrict__ fcw,
                                                        const float* __restrict__ fcb,
                                                        float* __restrict__ out) {
  __shared__ float red[4][HID];
  int g = blockIdx.x;
  int t = threadIdx.x;
  int c = t & 63, r = t >> 6;
  int s0 = gstart[g], s1 = gstart[g + 1];
  float acc = 0.f;
  for (int n = s0 + r; n < s1; n += 4) acc += o2[(size_t)n * HID + c];
  red[r][c] = acc;
  __syncthreads();
  if (r == 0) {                        // threads 0..63 = one wave
    float v = (red[0][c] + red[1][c] + red[2][c] + red[3][c])
              / fmaxf((float)(s1 - s0), 1.f);
    float p0 = v * fcw[c * 2 + 0];
    float p1 = v * fcw[c * 2 + 1];
#pragma unroll
    for (int o = 1; o < 64; o <<= 1) {
      p0 += __shfl_xor(p0, o, 64);
      p1 += __shfl_xor(p1, o, 64);
    }
    if (c == 0) {
      float l0 = p0 + fcb[0], l1 = p1 + fcb[1];
      float mx = fmaxf(l0, l1);
      float lse = mx + logf(expf(l0 - mx) + expf(l1 - mx));
      out[g * 2 + 0] = l0 - lse;
      out[g * 2 + 1] = l1 - lse;
    }
  }
}

// ---------------- launch ----------------
extern "C" void kernel_launch(void* const* d_in, const int* in_sizes, int n_in,
                              void* d_out, int out_size, void* d_ws, size_t ws_size,
                              hipStream_t stream) {
  const float* x    = (const float*)d_in[0];
  const int*   ei   = (const int*)d_in[1];
  const int*   batch= (const int*)d_in[2];
  const float* W1   = (const float*)d_in[3];
  const float* as1  = (const float*)d_in[4];
  const float* ad1  = (const float*)d_in[5];
  const float* b1   = (const float*)d_in[6];
  const float* W2   = (const float*)d_in[7];
  const float* as2  = (const float*)d_in[8];
  const float* ad2  = (const float*)d_in[9];
  const float* b2   = (const float*)d_in[10];
  const float* fcw  = (const float*)d_in[11];
  const float* fcb  = (const float*)d_in[12];
  float* out = (float*)d_out;
  float* ws  = (float*)d_ws;

  const int* esrc = ei;
  const int* edst = ei + NE;

  // ---- workspace layout (float units; qoff kept 16B-aligned) ----
  size_t off = 0;
  float* hreg  = ws + off; off += (size_t)NN * HC1 / 2;  // h1 fp16 [NN,256]
  float* o1reg = ws + off; off += (size_t)NN * HC1 / 2;  // o1 fp16 [NN,256]
  float* l2reg = ws + off; off += (size_t)NN * HC1 / 2;  // h2 fp16 [NN,64] + o2 fp32 [NN,64]
  float* ss1 = ws + off; off += (size_t)NN * HEADS;
  float* sd1 = ws + off; off += (size_t)NN * HEADS;
  float* ss2 = ws + off; off += NN;
  float* sd2 = ws + off; off += NN;
  __half* W1T = (__half*)(ws + off); off += (size_t)HC1 * F_IN / 2;
  __half* W2T = (__half*)(ws + off); off += (size_t)HID * HC1 / 2;
  int4* qoff   = (int4*)(ws + off); off += (size_t)NN * 4;     // 16B-aligned here
  int* rowptr  = (int*)(ws + off); off += NN + 1;
  int* ssorted = (int*)(ws + off); off += ETOT;
  int* gstart  = (int*)(ws + off); off += NG + 1;
  int* psum    = (int*)(ws + off); off += SCAN_B;
  int* deg4    = (int*)(ws + off); off += 4 * (size_t)NN;      // zeroed in csr_coop
  int* cursor4 = (int*)(ws + off); off += 4 * (size_t)NN;      // contiguous with deg4
  __half* h1  = (__half*)hreg;                         // [NN, 256] fp16
  __half* o1h = (__half*)o1reg;                        // [NN, 256] fp16
  __half* h2  = (__half*)l2reg;                        // [NN, 64] fp16
  float*  o2  = l2reg + (size_t)NN * HID / 2;          // [NN, 64] fp32

  // ---- CSR build + weight prep: ONE cooperative dispatch ----
  {
    void* args[] = {
      (void*)&esrc, (void*)&edst, (void*)&W1, (void*)&W2,
      (void*)&W1T, (void*)&W2T, (void*)&deg4, (void*)&cursor4,
      (void*)&rowptr, (void*)&qoff, (void*)&psum, (void*)&batch,
      (void*)&gstart, (void*)&ssorted
    };
    hipLaunchCooperativeKernel((void*)csr_coop_kernel, dim3(1024), dim3(256),
                               args, 0, stream);
  }

  // ---- layer 1 ----
  gemm1_mfma<<<NN / 16, 256, 0, stream>>>(x, W1T, as1, ad1, h1, ss1, sd1);
  gat_gather4_kernel<<<(NN + 3) / 4, 256, 0, stream>>>(rowptr, ssorted, ss1, sd1, h1, b1, o1h);

  // ---- layer 2 ----
  gemm2_mfma<<<NN / 16, 64, 0, stream>>>(o1h, W2T, as2, ad2, h2, ss2, sd2);
  gat_gather1_kernel<<<(NN + 3) / 4, 256, 0, stream>>>(rowptr, ssorted, ss2, sd2, h2, b2, o2);

  // ---- pool + head (fused) ----
  pool_head_kernel<<<NG, 256, 0, stream>>>(o2, gstart, fcw, fcb, out);
}

// Round 10
// 414.319 us; speedup vs baseline: 2.1814x; 2.1814x over previous
//
#include <hip/hip_runtime.h>
#include <hip/hip_fp16.h>
#include <math.h>

// ---------------- problem constants ----------------
constexpr int NN   = 50000;          // nodes
constexpr int NE   = 800000;         // edges (before self loops)
constexpr int ETOT = NE + NN;        // 850000 with self loops
constexpr int F_IN = 128;
constexpr int HID  = 64;
constexpr int HEADS = 4;
constexpr int HC1  = HEADS * HID;    // 256
constexpr int NG   = 64;             // graphs
constexpr float SLOPE = 0.2f;
constexpr int TW_TOT = F_IN * HC1 + HC1 * HID;   // transpose work items (49152)
constexpr int SCAN_B = 196;                       // scan chunks (196*256 >= NN)

typedef _Float16 half8 __attribute__((ext_vector_type(8)));
typedef float f32x4 __attribute__((ext_vector_type(4)));

__device__ __forceinline__ float lrelu(float v) { return v >= 0.f ? v : SLOPE * v; }
__device__ __forceinline__ float elu(float v) { return v > 0.f ? v : expm1f(v); }

// pack 8 floats -> 8 fp16 as one uint4
__device__ __forceinline__ uint4 pack8_h(const float* v) {
  union { __half2 h[4]; uint4 u; } pk;
  pk.h[0] = __floats2half2_rn(v[0], v[1]);
  pk.h[1] = __floats2half2_rn(v[2], v[3]);
  pk.h[2] = __floats2half2_rn(v[4], v[5]);
  pk.h[3] = __floats2half2_rn(v[6], v[7]);
  return pk.u;
}

// ================= CSR build (separate dispatches — coop grid.sync costs ~100µs each, measured R9) =====
// fused: 4-way split degree histogram (contention /4) + weight transposes
__global__ void deg_tw_kernel(const int* __restrict__ edst, int* __restrict__ deg4,
                              const float* __restrict__ W1, const float* __restrict__ W2,
                              __half* __restrict__ W1T, __half* __restrict__ W2T) {
  int idx = blockIdx.x * blockDim.x + threadIdx.x;
  if (idx < ETOT) {
    int d = (idx < NE) ? edst[idx] : (idx - NE);
    atomicAdd(&deg4[(idx & 3) * NN + d], 1);
  } else {
    int i = idx - ETOT;
    if (i < F_IN * HC1) {                       // W1 [128][256] -> W1T [256][128]
      int k = i / HC1, n = i - k * HC1;
      W1T[n * F_IN + k] = __float2half(W1[i]);
    } else if (i < TW_TOT) {                    // W2 [256][64] -> W2T [64][256]
      int j = i - F_IN * HC1;
      int k = j / HID, n = j - k * HID;
      W2T[n * HC1 + k] = __float2half(W2[j]);
    }
  }
}

// scan stage 1: sum 4 sub-histograms, per-dst quarter offsets, per-chunk scan
__global__ __launch_bounds__(256) void scan_part_kernel(const int* __restrict__ deg4,
                                                        int* __restrict__ rowptr,
                                                        int* __restrict__ psum,
                                                        int4* __restrict__ qoff) {
  __shared__ int wsum[4];
  const int t = threadIdx.x, lane = t & 63, w = t >> 6;
  const int i = blockIdx.x * 256 + t;
  int d0 = 0, d1 = 0, d2 = 0, d3 = 0;
  if (i < NN) {
    d0 = deg4[i]; d1 = deg4[NN + i]; d2 = deg4[2 * NN + i]; d3 = deg4[3 * NN + i];
    qoff[i] = make_int4(0, d0, d0 + d1, d0 + d1 + d2);
  }
  int sv = d0 + d1 + d2 + d3;
#pragma unroll
  for (int o = 1; o < 64; o <<= 1) {
    int u = __shfl_up(sv, o, 64);
    if (lane >= o) sv += u;
  }
  if (lane == 63) wsum[w] = sv;
  __syncthreads();
  if (t == 0) {
    int a = wsum[0];
    wsum[0] = 0;
    int b = a + wsum[1]; wsum[1] = a;
    a = b + wsum[2]; wsum[2] = b;
    b = a + wsum[3]; wsum[3] = a;
    psum[blockIdx.x] = b;
  }
  __syncthreads();
  if (i < NN) rowptr[i + 1] = sv + wsum[w];
}

// stage 2: exclusive scan of SCAN_B partials (single block) + graph boundaries
__global__ __launch_bounds__(256) void scan_top_kernel(int* __restrict__ psum,
                                                       int* __restrict__ rowptr,
                                                       const int* __restrict__ batch,
                                                       int* __restrict__ gstart) {
  __shared__ int wsum[4];
  const int t = threadIdx.x, lane = t & 63, w = t >> 6;
  int v = (t < SCAN_B) ? psum[t] : 0;
  int sv = v;
#pragma unroll
  for (int o = 1; o < 64; o <<= 1) {
    int u = __shfl_up(sv, o, 64);
    if (lane >= o) sv += u;
  }
  if (lane == 63) wsum[w] = sv;
  __syncthreads();
  if (t == 0) {
    int a = wsum[0];
    wsum[0] = 0;
    int b = a + wsum[1]; wsum[1] = a;
    a = b + wsum[2]; wsum[2] = b;
    wsum[3] = a;
    rowptr[0] = 0;
  }
  __syncthreads();
  if (t < SCAN_B) psum[t] = sv - v + wsum[w];   // exclusive chunk offset
  if (t < NG + 1) {
    int g = t, lo = 0, hi = NN;
    while (lo < hi) { int mid = (lo + hi) >> 1; if (batch[mid] < g) lo = mid + 1; else hi = mid; }
    gstart[g] = lo;
  }
}

// stage 3: add chunk offsets
__global__ __launch_bounds__(256) void scan_add_kernel(const int* __restrict__ psum,
                                                       int* __restrict__ rowptr) {
  const int i = blockIdx.x * 256 + threadIdx.x;
  if (i < NN) rowptr[i + 1] += psum[blockIdx.x];
}

// scatter with 4-way cursors (contention /4)
__global__ void scatter_kernel(const int* __restrict__ esrc, const int* __restrict__ edst,
                               const int* __restrict__ rowptr, const int4* __restrict__ qoff,
                               int* __restrict__ cursor4, int* __restrict__ ssorted) {
  int e = blockIdx.x * blockDim.x + threadIdx.x;
  if (e >= ETOT) return;
  int s = (e < NE) ? esrc[e] : (e - NE);
  int d = (e < NE) ? edst[e] : (e - NE);
  int q = e & 3;
  int4 qo = qoff[d];
  int base = (q == 0) ? qo.x : (q == 1) ? qo.y : (q == 2) ? qo.z : qo.w;
  int slot = rowptr[d] + base + atomicAdd(&cursor4[q * NN + d], 1);
  ssorted[slot] = s;
}

// ================= gemm1 (MFMA): h1 = fp16(x @ W1), + attention scores =================
__global__ __launch_bounds__(256) void gemm1_mfma(
    const float* __restrict__ x, const __half* __restrict__ W1T,
    const float* __restrict__ asrc, const float* __restrict__ adst,
    __half* __restrict__ h1, float* __restrict__ ssrc, float* __restrict__ sdst) {
  __shared__ float hs[16][HC1 + 1];
  const int m0 = blockIdx.x * 16;
  const int t = threadIdx.x;
  const int wv = t >> 6, lane = t & 63;
  const int lm = lane & 15, quad = lane >> 4;
  const int n0 = wv * 64;
  f32x4 acc[4] = {{0.f,0.f,0.f,0.f},{0.f,0.f,0.f,0.f},{0.f,0.f,0.f,0.f},{0.f,0.f,0.f,0.f}};
  const float* arow = x + (size_t)(m0 + lm) * F_IN + quad * 8;
#pragma unroll
  for (int kc = 0; kc < F_IN; kc += 32) {
    float4 u = *(const float4*)(arow + kc);
    float4 v = *(const float4*)(arow + kc + 4);
    half8 a;
    a[0]=(_Float16)u.x; a[1]=(_Float16)u.y; a[2]=(_Float16)u.z; a[3]=(_Float16)u.w;
    a[4]=(_Float16)v.x; a[5]=(_Float16)v.y; a[6]=(_Float16)v.z; a[7]=(_Float16)v.w;
#pragma unroll
    for (int tn = 0; tn < 4; ++tn) {
      half8 b = *(const half8*)(W1T + (size_t)(n0 + tn * 16 + lm) * F_IN + kc + quad * 8);
      acc[tn] = __builtin_amdgcn_mfma_f32_16x16x32_f16(a, b, acc[tn], 0, 0, 0);
    }
  }
#pragma unroll
  for (int tn = 0; tn < 4; ++tn)
#pragma unroll
    for (int r = 0; r < 4; ++r)
      hs[quad * 4 + r][n0 + tn * 16 + lm] = acc[tn][r];
  __syncthreads();
  {
    __half2* h1h = (__half2*)(h1 + (size_t)m0 * HC1);
    int c2 = t & 127, rbase = (t >> 7) * 8;
#pragma unroll
    for (int r = 0; r < 8; ++r) {
      int row = rbase + r;
      h1h[row * 128 + c2] = __floats2half2_rn(hs[row][2 * c2], hs[row][2 * c2 + 1]);
    }
  }
  if (t < 128) {
    int r = t >> 3, hh = (t >> 1) & 3, isdst = t & 1;
    const float* a = isdst ? adst : asrc;
    float s = 0.f;
    for (int c = 0; c < HID; ++c) s += hs[r][hh * HID + c] * a[hh * HID + c];
    (isdst ? sdst : ssrc)[(m0 + r) * HEADS + hh] = s;
  }
}

// ================= gemm2 (MFMA): h2 = fp16(o1 @ W2), + attention scores =================
// one wave per block; 16 rows x 64 cols (4 mfma tiles), K=256 in 8 chunks.
__global__ __launch_bounds__(64) void gemm2_mfma(
    const __half* __restrict__ o1h, const __half* __restrict__ W2T,
    const float* __restrict__ asrc, const float* __restrict__ adst,
    __half* __restrict__ h2, float* __restrict__ ssrc, float* __restrict__ sdst) {
  __shared__ float hs[16][HID + 1];
  const int m0 = blockIdx.x * 16;
  const int lane = threadIdx.x;
  const int lm = lane & 15, quad = lane >> 4;
  f32x4 acc[4] = {{0.f,0.f,0.f,0.f},{0.f,0.f,0.f,0.f},{0.f,0.f,0.f,0.f},{0.f,0.f,0.f,0.f}};
  const __half* arow = o1h + (size_t)(m0 + lm) * HC1 + quad * 8;
#pragma unroll
  for (int kc = 0; kc < HC1; kc += 32) {
    half8 a = *(const half8*)(arow + kc);
#pragma unroll
    for (int tn = 0; tn < 4; ++tn) {
      half8 b = *(const half8*)(W2T + (size_t)(tn * 16 + lm) * HC1 + kc + quad * 8);
      acc[tn] = __builtin_amdgcn_mfma_f32_16x16x32_f16(a, b, acc[tn], 0, 0, 0);
    }
  }
#pragma unroll
  for (int tn = 0; tn < 4; ++tn)
#pragma unroll
    for (int r = 0; r < 4; ++r)
      hs[quad * 4 + r][tn * 16 + lm] = acc[tn][r];
  __syncthreads();
  {
    __half2* h2h = (__half2*)(h2 + (size_t)m0 * HID);
    int c2 = lane & 31, rbase = (lane >> 5) * 8;
#pragma unroll
    for (int r = 0; r < 8; ++r) {
      int row = rbase + r;
      h2h[row * 32 + c2] = __floats2half2_rn(hs[row][2 * c2], hs[row][2 * c2 + 1]);
    }
  }
  if (lane < 32) {
    int r = lane >> 1, isdst = lane & 1;
    const float* a = isdst ? adst : asrc;
    float s = 0.f;
    for (int c = 0; c < HID; ++c) s += hs[r][c] * a[c];
    (isdst ? sdst : ssrc)[m0 + r] = s;
  }
}

// ================= fused GAT gather, layer 1 (H=4): one wave per dst =================
// Score phase: lane = j*4+h handles (edge j, head h), 16 edges/pass.
// Agg phase: 2 edges in flight: eg=lane>>5 takes edge j+eg; cpos=lane&31 covers
// 16B (8 fp16 channels) of the 512B row; head = cpos>>3. Output o1 in fp16.
__global__ __launch_bounds__(256) void gat_gather4_kernel(
    const int* __restrict__ rowptr, const int* __restrict__ ssorted,
    const float* __restrict__ ss, const float* __restrict__ sd,
    const __half* __restrict__ h, const float* __restrict__ bias,
    __half* __restrict__ outp) {
  const int d    = (blockIdx.x * 256 + threadIdx.x) >> 6;
  const int lane = threadIdx.x & 63;
  if (d >= NN) return;
  const int start = rowptr[d];
  const int deg   = rowptr[d + 1] - start;
  const int hsel  = lane & 3;     // score-phase head
  const int eg    = lane >> 5;    // agg edge subgroup (0/1)
  const int cpos  = lane & 31;    // 16B chunk within row
  const int hh    = cpos >> 3;    // agg-phase head
  const float sdv = sd[d * 4 + hsel];
  float accv[8] = {0.f,0.f,0.f,0.f,0.f,0.f,0.f,0.f};

  if (deg <= 32) {
    const int j0 = lane >> 2;
    int s0 = 0, s1 = 0;
    float v0 = -INFINITY, v1 = -INFINITY;
    if (j0 < deg)      { s0 = ssorted[start + j0];      v0 = lrelu(ss[s0 * 4 + hsel] + sdv); }
    if (j0 + 16 < deg) { s1 = ssorted[start + j0 + 16]; v1 = lrelu(ss[s1 * 4 + hsel] + sdv); }
    float mx = fmaxf(v0, v1);
#pragma unroll
    for (int o = 4; o < 64; o <<= 1) mx = fmaxf(mx, __shfl_xor(mx, o, 64));
    float p0 = (j0 < deg)      ? __expf(v0 - mx) : 0.f;
    float p1 = (j0 + 16 < deg) ? __expf(v1 - mx) : 0.f;
    float den = p0 + p1;
#pragma unroll
    for (int o = 4; o < 64; o <<= 1) den += __shfl_xor(den, o, 64);
    const float inv = 1.f / (den + 1e-16f);
    const float pa0 = p0 * inv, pa1 = p1 * inv;
    const int m1 = min(deg, 16);
    for (int j = 0; j < m1; j += 2) {
      int jj = j + eg;
      float alpha = (jj < m1) ? __shfl(pa0, jj * 4 + hh, 64) : 0.f;
      int   sj    = __shfl(s0, (jj < 16 ? jj : 15) * 4, 64);
      uint4 u = *(const uint4*)(h + (size_t)sj * HC1 + cpos * 8);
      float2 f0 = __half22float2(*(const __half2*)&u.x);
      float2 f1 = __half22float2(*(const __half2*)&u.y);
      float2 f2 = __half22float2(*(const __half2*)&u.z);
      float2 f3 = __half22float2(*(const __half2*)&u.w);
      accv[0] += alpha * f0.x; accv[1] += alpha * f0.y;
      accv[2] += alpha * f1.x; accv[3] += alpha * f1.y;
      accv[4] += alpha * f2.x; accv[5] += alpha * f2.y;
      accv[6] += alpha * f3.x; accv[7] += alpha * f3.y;
    }
    for (int j = 16; j < deg; j += 2) {
      int jj = j + eg - 16;
      float alpha = (jj + 16 < deg) ? __shfl(pa1, jj * 4 + hh, 64) : 0.f;
      int   sj    = __shfl(s1, (jj < 16 ? jj : 15) * 4, 64);
      uint4 u = *(const uint4*)(h + (size_t)sj * HC1 + cpos * 8);
      float2 f0 = __half22float2(*(const __half2*)&u.x);
      float2 f1 = __half22float2(*(const __half2*)&u.y);
      float2 f2 = __half22float2(*(const __half2*)&u.z);
      float2 f3 = __half22float2(*(const __half2*)&u.w);
      accv[0] += alpha * f0.x; accv[1] += alpha * f0.y;
      accv[2] += alpha * f1.x; accv[3] += alpha * f1.y;
      accv[4] += alpha * f2.x; accv[5] += alpha * f2.y;
      accv[6] += alpha * f3.x; accv[7] += alpha * f3.y;
    }
  } else {
    // chunked (rare)
    float mx = -INFINITY;
    for (int base = 0; base < deg; base += 16) {
      int j = base + (lane >> 2);
      float v = (j < deg) ? lrelu(ss[ssorted[start + j] * 4 + hsel] + sdv) : -INFINITY;
#pragma unroll
      for (int o = 4; o < 64; o <<= 1) v = fmaxf(v, __shfl_xor(v, o, 64));
      mx = fmaxf(mx, v);
    }
    float den = 0.f;
    for (int base = 0; base < deg; base += 16) {
      int j = base + (lane >> 2);
      float p = (j < deg) ? __expf(lrelu(ss[ssorted[start + j] * 4 + hsel] + sdv) - mx) : 0.f;
#pragma unroll
      for (int o = 4; o < 64; o <<= 1) p += __shfl_xor(p, o, 64);
      den += p;
    }
    const float inv = 1.f / (den + 1e-16f);
    for (int base = 0; base < deg; base += 16) {
      int j = base + (lane >> 2);
      int s = 0; float pa = 0.f;
      if (j < deg) {
        s = ssorted[start + j];
        pa = __expf(lrelu(ss[s * 4 + hsel] + sdv) - mx) * inv;
      }
      int cnt = min(16, deg - base);
      for (int jc = 0; jc < cnt; jc += 2) {
        int jj = jc + eg;
        float alpha = (jj < cnt) ? __shfl(pa, jj * 4 + hh, 64) : 0.f;
        int   sj    = __shfl(s, (jj < 16 ? jj : 15) * 4, 64);
        uint4 u = *(const uint4*)(h + (size_t)sj * HC1 + cpos * 8);
        float2 f0 = __half22float2(*(const __half2*)&u.x);
        float2 f1 = __half22float2(*(const __half2*)&u.y);
        float2 f2 = __half22float2(*(const __half2*)&u.z);
        float2 f3 = __half22float2(*(const __half2*)&u.w);
        accv[0] += alpha * f0.x; accv[1] += alpha * f0.y;
        accv[2] += alpha * f1.x; accv[3] += alpha * f1.y;
        accv[4] += alpha * f2.x; accv[5] += alpha * f2.y;
        accv[6] += alpha * f3.x; accv[7] += alpha * f3.y;
      }
    }
  }
  // combine the two edge subgroups, then lanes 0..31 write the 512B fp16 row
#pragma unroll
  for (int k = 0; k < 8; ++k) accv[k] += __shfl_xor(accv[k], 32, 64);
  if (eg == 0) {
    float e[8];
#pragma unroll
    for (int k = 0; k < 8; ++k) e[k] = elu(accv[k] + bias[cpos * 8 + k]);
    *(uint4*)(outp + (size_t)d * HC1 + cpos * 8) = pack8_h(e);
  }
}

// ================= fused GAT gather, layer 2 (H=1): one wave per dst =================
__global__ __launch_bounds__(256) void gat_gather1_kernel(
    const int* __restrict__ rowptr, const int* __restrict__ ssorted,
    const float* __restrict__ ss, const float* __restrict__ sd,
    const __half* __restrict__ h, const float* __restrict__ bias,
    float* __restrict__ outp) {
  const int d    = (blockIdx.x * 256 + threadIdx.x) >> 6;
  const int lane = threadIdx.x & 63;
  if (d >= NN) return;
  const int start = rowptr[d];
  const int deg   = rowptr[d + 1] - start;
  const int eg   = lane >> 3;     // edge subgroup (0..7)
  const int cpos = lane & 7;      // 16B chunk within 128B row
  const float sdv = sd[d];
  float accv[8] = {0.f,0.f,0.f,0.f,0.f,0.f,0.f,0.f};

  if (deg <= 64) {
    int s = 0; float v = -INFINITY;
    if (lane < deg) { s = ssorted[start + lane]; v = lrelu(ss[s] + sdv); }
    float mx = v;
#pragma unroll
    for (int o = 1; o < 64; o <<= 1) mx = fmaxf(mx, __shfl_xor(mx, o, 64));
    float p = (lane < deg) ? __expf(v - mx) : 0.f;
    float den = p;
#pragma unroll
    for (int o = 1; o < 64; o <<= 1) den += __shfl_xor(den, o, 64);
    const float pa = p / (den + 1e-16f);
    for (int j = 0; j < deg; j += 8) {
      int jj = j + eg;
      float alpha = (jj < deg) ? __shfl(pa, jj < 63 ? jj : 63, 64) : 0.f;
      int   sj    = __shfl(s, jj < 63 ? jj : 63, 64);
      uint4 u = *(const uint4*)(h + (size_t)sj * HID + cpos * 8);
      float2 f0 = __half22float2(*(const __half2*)&u.x);
      float2 f1 = __half22float2(*(const __half2*)&u.y);
      float2 f2 = __half22float2(*(const __half2*)&u.z);
      float2 f3 = __half22float2(*(const __half2*)&u.w);
      accv[0] += alpha * f0.x; accv[1] += alpha * f0.y;
      accv[2] += alpha * f1.x; accv[3] += alpha * f1.y;
      accv[4] += alpha * f2.x; accv[5] += alpha * f2.y;
      accv[6] += alpha * f3.x; accv[7] += alpha * f3.y;
    }
  } else {
    float mx = -INFINITY;
    for (int base = 0; base < deg; base += 64) {
      int j = base + lane;
      float v = (j < deg) ? lrelu(ss[ssorted[start + j]] + sdv) : -INFINITY;
#pragma unroll
      for (int o = 1; o < 64; o <<= 1) v = fmaxf(v, __shfl_xor(v, o, 64));
      mx = fmaxf(mx, v);
    }
    float den = 0.f;
    for (int base = 0; base < deg; base += 64) {
      int j = base + lane;
      float p = (j < deg) ? __expf(lrelu(ss[ssorted[start + j]] + sdv) - mx) : 0.f;
#pragma unroll
      for (int o = 1; o < 64; o <<= 1) p += __shfl_xor(p, o, 64);
      den += p;
    }
    const float inv = 1.f / (den + 1e-16f);
    for (int base = 0; base < deg; base += 64) {
      int j = base + lane;
      int s = 0; float pa = 0.f;
      if (j < deg) { s = ssorted[start + j]; pa = __expf(lrelu(ss[s] + sdv) - mx) * inv; }
      int cnt = min(64, deg - base);
      for (int jc = 0; jc < cnt; jc += 8) {
        int jj = jc + eg;
        float alpha = (jj < cnt) ? __shfl(pa, jj < 63 ? jj : 63, 64) : 0.f;
        int   sj    = __shfl(s, jj < 63 ? jj : 63, 64);
        uint4 u = *(const uint4*)(h + (size_t)sj * HID + cpos * 8);
        float2 f0 = __half22float2(*(const __half2*)&u.x);
        float2 f1 = __half22float2(*(const __half2*)&u.y);
        float2 f2 = __half22float2(*(const __half2*)&u.z);
        float2 f3 = __half22float2(*(const __half2*)&u.w);
        accv[0] += alpha * f0.x; accv[1] += alpha * f0.y;
        accv[2] += alpha * f1.x; accv[3] += alpha * f1.y;
        accv[4] += alpha * f2.x; accv[5] += alpha * f2.y;
        accv[6] += alpha * f3.x; accv[7] += alpha * f3.y;
      }
    }
  }
#pragma unroll
  for (int o = 8; o < 64; o <<= 1) {
#pragma unroll
    for (int k = 0; k < 8; ++k) accv[k] += __shfl_xor(accv[k], o, 64);
  }
  if (eg == 0) {
    float4 r0, r1;
    r0.x = elu(accv[0] + bias[cpos * 8 + 0]);
    r0.y = elu(accv[1] + bias[cpos * 8 + 1]);
    r0.z = elu(accv[2] + bias[cpos * 8 + 2]);
    r0.w = elu(accv[3] + bias[cpos * 8 + 3]);
    r1.x = elu(accv[4] + bias[cpos * 8 + 4]);
    r1.y = elu(accv[5] + bias[cpos * 8 + 5]);
    r1.z = elu(accv[6] + bias[cpos * 8 + 6]);
    r1.w = elu(accv[7] + bias[cpos * 8 + 7]);
    float* op = outp + (size_t)d * HID + cpos * 8;
    *(float4*)op = r0;
    *(float4*)(op + 4) = r1;
  }
}

// ---------------- fused pool + FC + log_softmax: one block per graph ----------------
__global__ __launch_bounds__(256) void pool_head_kernel(const float* __restrict__ o2,
                                                        const int* __restrict__ gstart,
                                                        const float* __restrict__ fcw,
                                                        const float* __restrict__ fcb,
                                                        float* __restrict__ out) {
  __shared__ float red[4][HID];
  int g = blockIdx.x;
  int t = threadIdx.x;
  int c = t & 63, r = t >> 6;
  int s0 = gstart[g], s1 = gstart[g + 1];
  float acc = 0.f;
  for (int n = s0 + r; n < s1; n += 4) acc += o2[(size_t)n * HID + c];
  red[r][c] = acc;
  __syncthreads();
  if (r == 0) {                        // threads 0..63 = one wave
    float v = (red[0][c] + red[1][c] + red[2][c] + red[3][c])
              / fmaxf((float)(s1 - s0), 1.f);
    float p0 = v * fcw[c * 2 + 0];
    float p1 = v * fcw[c * 2 + 1];
#pragma unroll
    for (int o = 1; o < 64; o <<= 1) {
      p0 += __shfl_xor(p0, o, 64);
      p1 += __shfl_xor(p1, o, 64);
    }
    if (c == 0) {
      float l0 = p0 + fcb[0], l1 = p1 + fcb[1];
      float mx = fmaxf(l0, l1);
      float lse = mx + logf(expf(l0 - mx) + expf(l1 - mx));
      out[g * 2 + 0] = l0 - lse;
      out[g * 2 + 1] = l1 - lse;
    }
  }
}

// ---------------- launch ----------------
extern "C" void kernel_launch(void* const* d_in, const int* in_sizes, int n_in,
                              void* d_out, int out_size, void* d_ws, size_t ws_size,
                              hipStream_t stream) {
  const float* x    = (const float*)d_in[0];
  const int*   ei   = (const int*)d_in[1];
  const int*   batch= (const int*)d_in[2];
  const float* W1   = (const float*)d_in[3];
  const float* as1  = (const float*)d_in[4];
  const float* ad1  = (const float*)d_in[5];
  const float* b1   = (const float*)d_in[6];
  const float* W2   = (const float*)d_in[7];
  const float* as2  = (const float*)d_in[8];
  const float* ad2  = (const float*)d_in[9];
  const float* b2   = (const float*)d_in[10];
  const float* fcw  = (const float*)d_in[11];
  const float* fcb  = (const float*)d_in[12];
  float* out = (float*)d_out;
  float* ws  = (float*)d_ws;

  const int* esrc = ei;
  const int* edst = ei + NE;

  // ---- workspace layout (float units; qoff kept 16B-aligned) ----
  size_t off = 0;
  float* hreg  = ws + off; off += (size_t)NN * HC1 / 2;  // h1 fp16 [NN,256]
  float* o1reg = ws + off; off += (size_t)NN * HC1 / 2;  // o1 fp16 [NN,256]
  float* l2reg = ws + off; off += (size_t)NN * HC1 / 2;  // h2 fp16 [NN,64] + o2 fp32 [NN,64]
  float* ss1 = ws + off; off += (size_t)NN * HEADS;
  float* sd1 = ws + off; off += (size_t)NN * HEADS;
  float* ss2 = ws + off; off += NN;
  float* sd2 = ws + off; off += NN;
  __half* W1T = (__half*)(ws + off); off += (size_t)HC1 * F_IN / 2;
  __half* W2T = (__half*)(ws + off); off += (size_t)HID * HC1 / 2;
  int4* qoff   = (int4*)(ws + off); off += (size_t)NN * 4;     // 16B-aligned here
  int* rowptr  = (int*)(ws + off); off += NN + 1;
  int* ssorted = (int*)(ws + off); off += ETOT;
  int* gstart  = (int*)(ws + off); off += NG + 1;
  int* psum    = (int*)(ws + off); off += SCAN_B;
  int* deg4    = (int*)(ws + off); off += 4 * (size_t)NN;      // zero-init
  int* cursor4 = (int*)(ws + off); off += 4 * (size_t)NN;      // contiguous with deg4
  __half* h1  = (__half*)hreg;                         // [NN, 256] fp16
  __half* o1h = (__half*)o1reg;                        // [NN, 256] fp16
  __half* h2  = (__half*)l2reg;                        // [NN, 64] fp16
  float*  o2  = l2reg + (size_t)NN * HID / 2;          // [NN, 64] fp32

  hipMemsetAsync(deg4, 0, 8 * (size_t)NN * sizeof(int), stream);

  // ---- CSR build + weight prep ----
  deg_tw_kernel<<<(ETOT + TW_TOT + 255) / 256, 256, 0, stream>>>(edst, deg4, W1, W2, W1T, W2T);
  scan_part_kernel<<<SCAN_B, 256, 0, stream>>>(deg4, rowptr, psum, qoff);
  scan_top_kernel<<<1, 256, 0, stream>>>(psum, rowptr, batch, gstart);
  scan_add_kernel<<<SCAN_B, 256, 0, stream>>>(psum, rowptr);
  scatter_kernel<<<(ETOT + 255) / 256, 256, 0, stream>>>(esrc, edst, rowptr, qoff,
                                                         cursor4, ssorted);

  // ---- layer 1 ----
  gemm1_mfma<<<NN / 16, 256, 0, stream>>>(x, W1T, as1, ad1, h1, ss1, sd1);
  gat_gather4_kernel<<<(NN + 3) / 4, 256, 0, stream>>>(rowptr, ssorted, ss1, sd1, h1, b1, o1h);

  // ---- layer 2 ----
  gemm2_mfma<<<NN / 16, 64, 0, stream>>>(o1h, W2T, as2, ad2, h2, ss2, sd2);
  gat_gather1_kernel<<<(NN + 3) / 4, 256, 0, stream>>>(rowptr, ssorted, ss2, sd2, h2, b2, o2);

  // ---- pool + head (fused) ----
  pool_head_kernel<<<NG, 256, 0, stream>>>(o2, gstart, fcw, fcb, out);
}